// Round 12
// baseline (109.815 us; speedup 1.0000x reference)
//
#include <hip/hip_runtime.h>
#include <stdint.h>

#define T_LEN 262144
#define S 64
#define SP1 65

// forward: L=32 outputs + W=4 warm-up, ONE chain per wave (TLP > ILP:
// R10 measured 2 chains/wave at half the waves runs 2x slower).
// 8192 chains -> 2048 blocks of 256 -> 8 blocks/CU -> 32 waves/CU (cap).
#define L_FWD 32
#define W_FWD 4
#define C_FWD (T_LEN / L_FWD)   // 8192

// backtrack: one THREAD per window. LB=8 outputs, VB=8 warm chase.
#define LB2 8
#define VB2 8
#define NW (T_LEN / LB2)        // 32768 windows -> 128 blocks of 256
#define PITCH (LB2 + 2)

// DPP cumulative-fmax step (old = own value, bound_ctrl=false). After
// shr1,2,4,8 + bcast15 + bcast31, lane 63 holds the wave-wide max.
template <int CTRL>
__device__ __forceinline__ float dpp_fmax_step(float v) {
    int t = __builtin_amdgcn_update_dpp(__float_as_int(v), __float_as_int(v),
                                        CTRL, 0xf, 0xf, false);
    return fmaxf(__int_as_float(t), v);
}

__device__ __forceinline__ float readlane_f(float v, int lane) {
    return __int_as_float(__builtin_amdgcn_readlane(__float_as_int(v), lane));
}

// Force a wave-uniform 64-bit mask into SGPRs so all subsequent mask math
// (ffs, and, cselect) compiles to SALU ops on the scalar pipe instead of
// VGPR-pair emulation on the VALU. Ballot IS uniform; this is a no-op
// semantically.
__device__ __forceinline__ unsigned long long uniform64(unsigned long long m) {
    unsigned int lo = (unsigned int)__builtin_amdgcn_readfirstlane((int)(unsigned int)m);
    unsigned int hi = (unsigned int)__builtin_amdgcn_readfirstlane((int)(unsigned int)(m >> 32));
    return ((unsigned long long)hi << 32) | lo;
}

// packed argmax key: all scores < 0 -> u32-min on raw bits == float-max;
// low 6 bits carry j, tie-break = first occurrence (smaller j).
__device__ __forceinline__ unsigned int pack_key(float a, int j) {
    return (__float_as_uint(a) & 0xFFFFFFC0u) | (unsigned)j;
}

// k0: column-min pruning bound Mc[j] = min_i(rowmin_i - trans[i][j]) <= 0.
// Exact necessity: winner j of any row satisfies c_j >= cmax + Mc[j].
// Also zeroes the score accumulator.
__global__ __launch_bounds__(64) void k0_mc(const float* __restrict__ trans,
                                            float* __restrict__ wsMc,
                                            float* __restrict__ out_score) {
    __shared__ float st[S * S];
    __shared__ float rowmin[S];
    const int lane = threadIdx.x;
    for (int i = 0; i < S; ++i)
        st[i * S + lane] = trans[i * SP1 + lane];
    __syncthreads();
    float rm = 3.0e38f;
    for (int j = 0; j < S; ++j)
        rm = fminf(rm, st[lane * S + j]);
    rowmin[lane] = rm;
    __syncthreads();
    float mc = 3.0e38f;
    for (int i = 0; i < S; ++i)
        mc = fminf(mc, rowmin[i] - st[i * S + lane]);
    wsMc[lane] = mc;
    if (lane == 0) out_score[0] = 0.0f;
}

// k1: chunked forward Viterbi, one chain per wave, 4 chains/block,
// 8 blocks/CU. Loads-only steady-state vmcnt queue (bp bytes packed
// 4/dword in registers, burst-stored at chunk end). Survivor mask math
// forced scalar (uniform64). Eager-2 + conditional-2 + rare while.
__global__ __launch_bounds__(256, 8) void k1_forward(
    const int* __restrict__ rolls, const float* __restrict__ trans,
    const float* __restrict__ ll, const float* __restrict__ wsMc,
    unsigned int* __restrict__ bp4, int* __restrict__ wsFinal) {
    __shared__ float strans[S * S];  // strans[j*64 + i] = trans[i][j]
    const int tid = threadIdx.x;
    const int lane = tid & 63;
    const int wv = tid >> 6;

    for (int k = tid; k < S * S; k += 256)
        strans[k] = trans[(k & 63) * SP1 + (k >> 6)];  // transposed stage
    const float mcol = wsMc[lane];
    __syncthreads();

    const int c = blockIdx.x * 4 + wv;
    const int beg_out = c * L_FWD;
    int t0 = beg_out - W_FWD;
    if (t0 < 1) t0 = 1;

    // rolls for the whole chunk (plus prefetch slack) in one VGPR
    int vroll = rolls[min(t0 + lane, T_LEN - 1)];

    float delta;
    if (c == 0) {
        delta = trans[lane * SP1 + S] + ll[rolls[0] * S + lane];  // exact init
    } else {
        delta = 0.0f;  // arbitrary; warm-up coalesces (up to additive const)
    }

    // ll pipeline: ll_cur for step t, ll_nxt for t+1; issue t+2 in-loop
    int r0 = __builtin_amdgcn_readlane(vroll, 0);
    int r1 = __builtin_amdgcn_readlane(vroll, 1);
    float ll_cur = ll[r0 * S + lane];
    float ll_nxt = ll[r1 * S + lane];

    int idx = 0;  // t - t0

    auto step = [&]() -> unsigned int {
        int rp = __builtin_amdgcn_readlane(vroll, idx + 2);
        float ll_new = ll[rp * S + lane];  // used at t+2

        float cvec = delta + ll_cur;  // < 0 always

        // exact wave-wide max via fused dpp fmax chain
        float mxc = cvec;
        mxc = dpp_fmax_step<0x111>(mxc);
        mxc = dpp_fmax_step<0x112>(mxc);
        mxc = dpp_fmax_step<0x114>(mxc);
        mxc = dpp_fmax_step<0x118>(mxc);
        mxc = dpp_fmax_step<0x142>(mxc);
        mxc = dpp_fmax_step<0x143>(mxc);
        float cmax = readlane_f(mxc, 63);

        // exact per-lane pruning: survivors satisfy c_j >= cmax + Mc[j];
        // argmax lane always present (Mc <= 0)
        float thr = cmax + mcol;
        unsigned long long mask = uniform64(__ballot(cvec >= thr));  // SGPRs

        int j0 = __ffsll(mask) - 1;
        unsigned long long rm = mask & (mask - 1);
        int j1 = rm ? (__ffsll(rm) - 1) : j0;
        float a0 = strans[(j0 << 6) | lane] + readlane_f(cvec, j0);
        float a1 = strans[(j1 << 6) | lane] + readlane_f(cvec, j1);
        unsigned int m = min(pack_key(a0, j0), pack_key(a1, j1));

        unsigned long long rest = rm ? (rm & (rm - 1)) : 0ull;
        if (rest) {  // wave-uniform scalar branch; ~1/3 of steps
            int j2 = __ffsll(rest) - 1;
            unsigned long long r3 = rest & (rest - 1);
            int j3 = r3 ? (__ffsll(r3) - 1) : j2;
            float a2 = strans[(j2 << 6) | lane] + readlane_f(cvec, j2);
            float a3 = strans[(j3 << 6) | lane] + readlane_f(cvec, j3);
            m = min(m, min(pack_key(a2, j2), pack_key(a3, j3)));
            rest = r3 ? (r3 & (r3 - 1)) : 0ull;
            while (rest) {  // rare (>4 survivors)
                int j = __ffsll(rest) - 1;
                rest &= (rest - 1);
                float a = strans[(j << 6) | lane] + readlane_f(cvec, j);
                m = min(m, pack_key(a, j));
            }
        }

        delta = __uint_as_float(m & 0xFFFFFFC0u);  // quantized (~2^-15 rel)
        ll_cur = ll_nxt;
        ll_nxt = ll_new;
        ++idx;
        return m;
    };

    // warm-up: exactly W_FWD steps for c>0 (c==0 starts exact at t=1)
    if (c != 0) {
        #pragma unroll
        for (int w = 0; w < W_FWD; ++w)
            (void)step();
    }

    // main: 8 packed dwords accumulated in registers; burst store at end
    const int qb = beg_out >> 2;
    unsigned int pk[8];
    {   // q = 0: c==0 covers t=1..3 only (byte 0 never read by backtrack)
        unsigned int p = 0u;
        int u0 = (c == 0) ? 1 : 0;
        for (int u = u0; u < 4; ++u) {
            unsigned int m = step();
            p = (p >> 8) | ((m & 63u) << 24);
        }
        pk[0] = p;
    }
    #pragma unroll
    for (int q = 1; q < 8; ++q) {
        unsigned int p = 0u;
        #pragma unroll
        for (int u = 0; u < 4; ++u) {
            unsigned int m = step();
            p = (p >> 8) | ((m & 63u) << 24);
        }
        pk[q] = p;
    }
    #pragma unroll
    for (int q = 0; q < 8; ++q)
        bp4[(unsigned)((qb + q) << 6) | (unsigned)lane] = pk[q];

    if (c == C_FWD - 1) {
        float fmx = delta;
        for (int off = 32; off; off >>= 1)
            fmx = fmaxf(fmx, __shfl_xor(fmx, off));
        unsigned long long em = uniform64(__ballot(delta == fmx));
        if (lane == 0)
            *wsFinal = __ffsll(em) - 1;
    }
}

// k2: one THREAD per window. Chase 15 dependent gathers from te=thi+VB2
// (single seed; bp columns concentrate on ~2 survivors so backward chains
// coalesce inside VB2=8), record s[tlo..thi+1] in LDS, write the path,
// then score own window with neighbor-stitched boundary; one atomic/block.
__global__ __launch_bounds__(256) void k2_backtrack(
    const unsigned int* __restrict__ bp4, const int* __restrict__ wsFinal,
    const int* __restrict__ rolls, const float* __restrict__ trans,
    const float* __restrict__ ll, float* __restrict__ out_path,
    float* __restrict__ out_score) {
    __shared__ int sst[256 * PITCH];
    __shared__ float spart[4];
    const int tid = threadIdx.x;
    const int b = blockIdx.x * 256 + tid;   // window id
    const int tlo = b * LB2;
    const int thi = tlo + LB2 - 1;
    int te = thi + VB2;
    int s;
    if (te >= T_LEN - 1) {
        te = T_LEN - 1;
        s = *wsFinal;   // exact seed for the tail windows
    } else {
        s = 0;          // arbitrary; chase coalesces
    }
    int* row = sst + tid * PITCH;
    #pragma unroll
    for (int u = 0; u < LB2 + VB2 - 1; ++u) {  // 15 dependent gathers max
        int t = te - u;
        if (t > tlo) {
            if (t <= thi + 1) row[t - tlo] = s;
            unsigned int w = bp4[((unsigned)(t >> 2) << 6) | (unsigned)s];
            s = (int)((w >> ((t & 3) << 3)) & 63u);
        }
    }
    row[0] = s;  // state at tlo
    __syncthreads();

    // path write: out[T-1-t] = s_t for t in [tlo, thi]
    #pragma unroll
    for (int u = 0; u < LB2; ++u)
        out_path[T_LEN - 1 - (tlo + u)] = (float)row[u];

    // score terms: t in [tlo+1, thi+1] (clamped to T-1):
    //   trans[s_t][s_{t-1}] + ll[rolls[t]][s_{t-1}]
    // boundary s_{thi+1}: neighbor thread's row[0] (the state actually
    // emitted); tid==255 uses own chase state at thi+1.
    float acc = 0.0f;
    #pragma unroll
    for (int u = 1; u <= LB2; ++u) {
        int t = tlo + u;
        if (t <= T_LEN - 1) {
            int sp = row[u - 1];
            int st = (u == LB2)
                         ? ((tid < 255) ? sst[(tid + 1) * PITCH] : row[LB2])
                         : row[u];
            acc += trans[st * SP1 + sp] + ll[rolls[t] * S + sp];
        }
    }
    if (b == 0) {  // init term
        int s0 = row[0];
        acc += trans[s0 * SP1 + S] + ll[rolls[0] * S + s0];
    }

    for (int off = 32; off; off >>= 1)
        acc += __shfl_xor(acc, off);
    if ((tid & 63) == 0) spart[tid >> 6] = acc;
    __syncthreads();
    if (tid == 0)
        atomicAdd(out_score, (spart[0] + spart[1]) + (spart[2] + spart[3]));
}

extern "C" void kernel_launch(void* const* d_in, const int* in_sizes, int n_in,
                              void* d_out, int out_size, void* d_ws, size_t ws_size,
                              hipStream_t stream) {
    const int* rolls = (const int*)d_in[0];
    const float* trans = (const float*)d_in[1];   // (64, 65)
    const float* ll = (const float*)d_in[2];      // (128, 64)
    float* out = (float*)d_out;                   // [0..T): path (reverse), [T]: score
    char* ws = (char*)d_ws;
    int* wsFinal = (int*)(ws + 8);
    float* wsMc = (float*)(ws + 1024);              // 256 B
    unsigned int* bp4 = (unsigned int*)(ws + 2048); // 16 MiB packed bp

    k0_mc<<<1, 64, 0, stream>>>(trans, wsMc, out + T_LEN);
    k1_forward<<<C_FWD / 4, 256, 0, stream>>>(rolls, trans, ll, wsMc, bp4, wsFinal);
    k2_backtrack<<<NW / 256, 256, 0, stream>>>(bp4, wsFinal, rolls, trans, ll,
                                               out, out + T_LEN);
}

// Round 13
// 109.330 us; speedup vs baseline: 1.0044x; 1.0044x over previous
//
#include <hip/hip_runtime.h>
#include <hip/hip_fp16.h>
#include <stdint.h>

#define T_LEN 262144
#define S 64
#define SP1 65

// forward: L=32 outputs + W=4 warm-up, ONE chain per wave (TLP > ILP:
// R10 measured 2 chains/wave at half the waves runs 2x slower).
// 8192 chains -> 2048 blocks of 256 -> 8 blocks/CU target residency.
#define L_FWD 32
#define W_FWD 4
#define C_FWD (T_LEN / L_FWD)   // 8192

// backtrack: one THREAD per window. LB=8 outputs, VB=8 warm chase.
#define LB2 8
#define VB2 8
#define NW (T_LEN / LB2)        // 32768 windows -> 128 blocks of 256
#define PITCH (LB2 + 2)

// DPP cumulative-fmax step (old = own value, bound_ctrl=false). After
// shr1,2,4,8 + bcast15 + bcast31, lane 63 holds the wave-wide max.
template <int CTRL>
__device__ __forceinline__ float dpp_fmax_step(float v) {
    int t = __builtin_amdgcn_update_dpp(__float_as_int(v), __float_as_int(v),
                                        CTRL, 0xf, 0xf, false);
    return fmaxf(__int_as_float(t), v);
}

__device__ __forceinline__ float readlane_f(float v, int lane) {
    return __int_as_float(__builtin_amdgcn_readlane(__float_as_int(v), lane));
}

// packed argmax key: all scores < 0 -> u32-min on raw bits == float-max;
// low 6 bits carry j, tie-break = first occurrence (smaller j).
__device__ __forceinline__ unsigned int pack_key(float a, int j) {
    return (__float_as_uint(a) & 0xFFFFFFC0u) | (unsigned)j;
}

// k1: chunked forward Viterbi, one chain per wave, 4 chains/block.
// strans staged as fp16 (8 KB LDS) to test/raise block residency per CU.
// Per-block Mc (column-min pruning bound, computed from the SAME fp16
// trans the update uses -> bound stays exact for the computation done):
// Mc[j] = min_i(rowmin_i - trans[i][j]) <= 0; winner j of any row
// satisfies c_j >= cmax + Mc[j]. Loads-only steady-state vmcnt queue;
// bp bytes packed 4/dword in registers, burst-stored at chunk end.
__global__ __launch_bounds__(256, 8) void k1_forward(
    const int* __restrict__ rolls, const float* __restrict__ trans,
    const float* __restrict__ ll,
    unsigned int* __restrict__ bp4, int* __restrict__ wsFinal,
    float* __restrict__ out_score) {
    __shared__ __half strans_h[S * S];  // strans_h[j*64 + i] = trans[i][j]
    __shared__ float srowmin[S];
    __shared__ float sMc[S];
    const int tid = threadIdx.x;
    const int lane = tid & 63;
    const int wv = tid >> 6;

    if (blockIdx.x == 0 && tid == 0)
        out_score[0] = 0.0f;  // k2 is stream-ordered after k1 -> safe

    for (int k = tid; k < S * S; k += 256)
        strans_h[k] = __float2half(trans[(k & 63) * SP1 + (k >> 6)]);
    __syncthreads();

    // per-block Mc: rowmin_i = min_j trans[i][j]; Mc[j] = min_i(rowmin_i - trans[i][j])
    {
        int i = tid >> 2, q = tid & 3;
        float mn = 3.0e38f;
        #pragma unroll
        for (int u = 0; u < 16; ++u)
            mn = fminf(mn, __half2float(strans_h[((q * 16 + u) << 6) | i]));
        mn = fminf(mn, __shfl_xor(mn, 1));
        mn = fminf(mn, __shfl_xor(mn, 2));
        if (q == 0) srowmin[i] = mn;
    }
    __syncthreads();
    {
        int j = tid >> 2, q = tid & 3;
        float mc = 3.0e38f;
        #pragma unroll
        for (int u = 0; u < 16; ++u) {
            int i = q * 16 + u;
            mc = fminf(mc, srowmin[i] - __half2float(strans_h[(j << 6) | i]));
        }
        mc = fminf(mc, __shfl_xor(mc, 1));
        mc = fminf(mc, __shfl_xor(mc, 2));
        if (q == 0) sMc[j] = mc;
    }
    __syncthreads();
    const float mcol = sMc[lane];

    const int c = blockIdx.x * 4 + wv;
    const int beg_out = c * L_FWD;
    int t0 = beg_out - W_FWD;
    if (t0 < 1) t0 = 1;

    // rolls for the whole chunk (plus prefetch slack) in one VGPR
    int vroll = rolls[min(t0 + lane, T_LEN - 1)];

    float delta;
    if (c == 0) {
        delta = trans[lane * SP1 + S] + ll[rolls[0] * S + lane];  // exact init
    } else {
        delta = 0.0f;  // arbitrary; warm-up coalesces (up to additive const)
    }

    // ll pipeline: ll_cur for step t, ll_nxt for t+1; issue t+2 in-loop
    int r0 = __builtin_amdgcn_readlane(vroll, 0);
    int r1 = __builtin_amdgcn_readlane(vroll, 1);
    float ll_cur = ll[r0 * S + lane];
    float ll_nxt = ll[r1 * S + lane];

    int idx = 0;  // t - t0

    auto step = [&]() -> unsigned int {
        int rp = __builtin_amdgcn_readlane(vroll, idx + 2);
        float ll_new = ll[rp * S + lane];  // used at t+2

        float cvec = delta + ll_cur;  // < 0 always

        // exact wave-wide max via fused dpp fmax chain
        float mxc = cvec;
        mxc = dpp_fmax_step<0x111>(mxc);
        mxc = dpp_fmax_step<0x112>(mxc);
        mxc = dpp_fmax_step<0x114>(mxc);
        mxc = dpp_fmax_step<0x118>(mxc);
        mxc = dpp_fmax_step<0x142>(mxc);
        mxc = dpp_fmax_step<0x143>(mxc);
        float cmax = readlane_f(mxc, 63);

        // exact per-lane pruning: survivors satisfy c_j >= cmax + Mc[j];
        // argmax lane always present (Mc <= 0)
        float thr = cmax + mcol;
        unsigned long long mask = __ballot(cvec >= thr);

        int j0 = __ffsll(mask) - 1;
        unsigned long long rm = mask & (mask - 1);
        int j1 = rm ? (__ffsll(rm) - 1) : j0;
        float a0 = __half2float(strans_h[(j0 << 6) | lane]) + readlane_f(cvec, j0);
        float a1 = __half2float(strans_h[(j1 << 6) | lane]) + readlane_f(cvec, j1);
        unsigned int m = min(pack_key(a0, j0), pack_key(a1, j1));

        unsigned long long rest = rm ? (rm & (rm - 1)) : 0ull;
        if (rest) {  // wave-uniform scalar branch; ~1/3 of steps
            int j2 = __ffsll(rest) - 1;
            unsigned long long r3 = rest & (rest - 1);
            int j3 = r3 ? (__ffsll(r3) - 1) : j2;
            float a2 = __half2float(strans_h[(j2 << 6) | lane]) + readlane_f(cvec, j2);
            float a3 = __half2float(strans_h[(j3 << 6) | lane]) + readlane_f(cvec, j3);
            m = min(m, min(pack_key(a2, j2), pack_key(a3, j3)));
            rest = r3 ? (r3 & (r3 - 1)) : 0ull;
            while (rest) {  // rare (>4 survivors)
                int j = __ffsll(rest) - 1;
                rest &= (rest - 1);
                float a = __half2float(strans_h[(j << 6) | lane]) + readlane_f(cvec, j);
                m = min(m, pack_key(a, j));
            }
        }

        delta = __uint_as_float(m & 0xFFFFFFC0u);  // quantized (~2^-15 rel)
        ll_cur = ll_nxt;
        ll_nxt = ll_new;
        ++idx;
        return m;
    };

    // warm-up: exactly W_FWD steps for c>0 (c==0 starts exact at t=1)
    if (c != 0) {
        #pragma unroll
        for (int w = 0; w < W_FWD; ++w)
            (void)step();
    }

    // main: 8 packed dwords accumulated in registers; burst store at end
    const int qb = beg_out >> 2;
    unsigned int pk[8];
    {   // q = 0: c==0 covers t=1..3 only (byte 0 never read by backtrack)
        unsigned int p = 0u;
        int u0 = (c == 0) ? 1 : 0;
        for (int u = u0; u < 4; ++u) {
            unsigned int m = step();
            p = (p >> 8) | ((m & 63u) << 24);
        }
        pk[0] = p;
    }
    #pragma unroll
    for (int q = 1; q < 8; ++q) {
        unsigned int p = 0u;
        #pragma unroll
        for (int u = 0; u < 4; ++u) {
            unsigned int m = step();
            p = (p >> 8) | ((m & 63u) << 24);
        }
        pk[q] = p;
    }
    #pragma unroll
    for (int q = 0; q < 8; ++q)
        bp4[(unsigned)((qb + q) << 6) | (unsigned)lane] = pk[q];

    if (c == C_FWD - 1) {
        float fmx = delta;
        for (int off = 32; off; off >>= 1)
            fmx = fmaxf(fmx, __shfl_xor(fmx, off));
        unsigned long long em = __ballot(delta == fmx);
        if (lane == 0)
            *wsFinal = __ffsll(em) - 1;
    }
}

// k2: one THREAD per window. Chase 15 dependent gathers from te=thi+VB2
// (single seed; bp columns concentrate on ~2 survivors so backward chains
// coalesce inside VB2=8), record s[tlo..thi+1] in LDS, write the path,
// then score own window with neighbor-stitched boundary; one atomic/block.
// Scoring uses fp32 tables -> returned score is exact for the emitted path.
__global__ __launch_bounds__(256) void k2_backtrack(
    const unsigned int* __restrict__ bp4, const int* __restrict__ wsFinal,
    const int* __restrict__ rolls, const float* __restrict__ trans,
    const float* __restrict__ ll, float* __restrict__ out_path,
    float* __restrict__ out_score) {
    __shared__ int sst[256 * PITCH];
    __shared__ float spart[4];
    const int tid = threadIdx.x;
    const int b = blockIdx.x * 256 + tid;   // window id
    const int tlo = b * LB2;
    const int thi = tlo + LB2 - 1;
    int te = thi + VB2;
    int s;
    if (te >= T_LEN - 1) {
        te = T_LEN - 1;
        s = *wsFinal;   // exact seed for the tail windows
    } else {
        s = 0;          // arbitrary; chase coalesces
    }
    int* row = sst + tid * PITCH;
    #pragma unroll
    for (int u = 0; u < LB2 + VB2 - 1; ++u) {  // 15 dependent gathers max
        int t = te - u;
        if (t > tlo) {
            if (t <= thi + 1) row[t - tlo] = s;
            unsigned int w = bp4[((unsigned)(t >> 2) << 6) | (unsigned)s];
            s = (int)((w >> ((t & 3) << 3)) & 63u);
        }
    }
    row[0] = s;  // state at tlo
    __syncthreads();

    // path write: out[T-1-t] = s_t for t in [tlo, thi]
    #pragma unroll
    for (int u = 0; u < LB2; ++u)
        out_path[T_LEN - 1 - (tlo + u)] = (float)row[u];

    // score terms: t in [tlo+1, thi+1] (clamped to T-1):
    //   trans[s_t][s_{t-1}] + ll[rolls[t]][s_{t-1}]
    // boundary s_{thi+1}: neighbor thread's row[0] (the state actually
    // emitted); tid==255 uses own chase state at thi+1.
    float acc = 0.0f;
    #pragma unroll
    for (int u = 1; u <= LB2; ++u) {
        int t = tlo + u;
        if (t <= T_LEN - 1) {
            int sp = row[u - 1];
            int st = (u == LB2)
                         ? ((tid < 255) ? sst[(tid + 1) * PITCH] : row[LB2])
                         : row[u];
            acc += trans[st * SP1 + sp] + ll[rolls[t] * S + sp];
        }
    }
    if (b == 0) {  // init term
        int s0 = row[0];
        acc += trans[s0 * SP1 + S] + ll[rolls[0] * S + s0];
    }

    for (int off = 32; off; off >>= 1)
        acc += __shfl_xor(acc, off);
    if ((tid & 63) == 0) spart[tid >> 6] = acc;
    __syncthreads();
    if (tid == 0)
        atomicAdd(out_score, (spart[0] + spart[1]) + (spart[2] + spart[3]));
}

extern "C" void kernel_launch(void* const* d_in, const int* in_sizes, int n_in,
                              void* d_out, int out_size, void* d_ws, size_t ws_size,
                              hipStream_t stream) {
    const int* rolls = (const int*)d_in[0];
    const float* trans = (const float*)d_in[1];   // (64, 65)
    const float* ll = (const float*)d_in[2];      // (128, 64)
    float* out = (float*)d_out;                   // [0..T): path (reverse), [T]: score
    char* ws = (char*)d_ws;
    int* wsFinal = (int*)(ws + 8);
    unsigned int* bp4 = (unsigned int*)(ws + 2048); // 16 MiB packed bp

    k1_forward<<<C_FWD / 4, 256, 0, stream>>>(rolls, trans, ll, bp4, wsFinal,
                                              out + T_LEN);
    k2_backtrack<<<NW / 256, 256, 0, stream>>>(bp4, wsFinal, rolls, trans, ll,
                                               out, out + T_LEN);
}